// Round 2
// baseline (1258.197 us; speedup 1.0000x reference)
//
#include <hip/hip_runtime.h>
#include <hip/hip_bf16.h>

// FLASH/GAU block: B=4 N=4096 DIM=1024 HID=2048 QK=128 G=256
// All GEMMs via one templated bf16 MFMA kernel (128x128x32 tile, 4 waves,
// 16x16x32 MFMA, fp32 accum) with fused per-mode epilogues.
// Workspace plan (~225 MB): arena R = [normed|whb|qq|qkk|linkT|pkv] (68 MB);
// `gated` (64 MB) aliases R[0..64M) -- every member of R is dead before the
// first mode-3 write, and mode 3 reads only buffers outside R.

typedef __attribute__((ext_vector_type(8))) short short8;
typedef __attribute__((ext_vector_type(4))) float f32x4;

union U8 { short8 v; unsigned short u[8]; };

#define BM 128
#define BN 128
#define BK 32
#define BKP 40   // padded LDS leading dim (bf16 elems) to break bank conflicts

struct Aux {
  const float* b1;              // bias vec (b_h / b_qk / b_out)
  const float* x;               // residual (mode6)
  const float* gamma;           // os_gamma (mode1)
  const float* beta;            // os_beta  (mode1)
  const float* biastab;         // rel-pos table (mode2)
  const unsigned short* a2;     // mode3: lin_q (16384x128 bf16)
  const unsigned short* bkv;    // mode3: lin_kv (4x128x2048 bf16)
  const unsigned short* gate;   // mode3: bf16 gate
  unsigned short* o16a;
  unsigned short* o16b;
  unsigned short* o16c;
  unsigned short* o16d;
  float* o32;
};

__device__ __forceinline__ float bf2f(unsigned short u) {
  union { float f; unsigned int i; } w; w.i = ((unsigned int)u) << 16; return w.f;
}
__device__ __forceinline__ unsigned short f2bf(float f) {
  union { float f; unsigned int i; } w; w.f = f;
  unsigned int x = w.i;
  return (unsigned short)((x + 0x7FFFu + ((x >> 16) & 1u)) >> 16);
}
__device__ __forceinline__ float silu_f(float z) { return z / (1.0f + __expf(-z)); }

__device__ __forceinline__ float block_sum(float v) {
  #pragma unroll
  for (int o = 32; o > 0; o >>= 1) v += __shfl_down(v, o, 64);
  __shared__ float sh[4];
  __syncthreads();
  if ((threadIdx.x & 63) == 0) sh[threadIdx.x >> 6] = v;
  __syncthreads();
  return sh[0] + sh[1] + sh[2] + sh[3];
}

// LayerNorm over DIM=1024, one block per row, output bf16.
__global__ __launch_bounds__(256) void ln_k(const float* __restrict__ x,
                                            const float* __restrict__ g,
                                            const float* __restrict__ b,
                                            unsigned short* __restrict__ out) {
  const int row = blockIdx.x;
  const int tid = threadIdx.x;
  const float4 xv = ((const float4*)(x + (size_t)row * 1024))[tid];
  float s = xv.x + xv.y + xv.z + xv.w;
  s = block_sum(s);
  const float mu = s * (1.0f / 1024.0f);
  const float d0 = xv.x - mu, d1 = xv.y - mu, d2 = xv.z - mu, d3 = xv.w - mu;
  float q = d0 * d0 + d1 * d1 + d2 * d2 + d3 * d3;
  q = block_sum(q);
  const float rstd = rsqrtf(q * (1.0f / 1024.0f) + 1e-5f);
  const float4 gv = ((const float4*)g)[tid];
  const float4 bv = ((const float4*)b)[tid];
  unsigned short* o = out + (size_t)row * 1024 + tid * 4;
  o[0] = f2bf(d0 * rstd * gv.x + bv.x);
  o[1] = f2bf(d1 * rstd * gv.y + bv.y);
  o[2] = f2bf(d2 * rstd * gv.z + bv.z);
  o[3] = f2bf(d3 * rstd * gv.w + bv.w);
}

// fp32 -> bf16 cast (x4 vectorized); n4 = number of float4 groups
__global__ void cast_k(const float* __restrict__ in, unsigned short* __restrict__ out, int n4) {
  int i = blockIdx.x * 256 + threadIdx.x;
  if (i >= n4) return;
  float4 f = ((const float4*)in)[i];
  ushort4 u;
  u.x = f2bf(f.x); u.y = f2bf(f.y); u.z = f2bf(f.z); u.w = f2bf(f.w);
  ((ushort4*)out)[i] = u;
}

// rel-pos bias table: tab[d + 255] for d = j - i in [-255, 255]
__global__ void bias_k(const float* __restrict__ rel, float* __restrict__ tab) {
  int idx = blockIdx.x * 256 + threadIdx.x;
  if (idx >= 511) return;
  int d = idx - 255;       // j - i
  int n = -d;              // i - j
  int ret = (n < 0) ? 16 : 0;
  int a = (n < 0) ? -n : n;
  int bucket;
  if (a < 8) {
    bucket = ret + a;
  } else {
    // mirror f32: log(a/8) / log(16) * 8, truncate
    float t = __logf((float)a * 0.125f) / 2.7725887298583984f * 8.0f;
    int vl = 8 + (int)t;
    if (vl > 15) vl = 15;
    bucket = ret + vl;
  }
  tab[idx] = rel[bucket] * 11.313708498984761f;  // * sqrt(QK)
}

// reduce 4 split-K partials of lin_kv, scale 1/N, cast bf16
__global__ void kvred_k(const float* __restrict__ pkv, unsigned short* __restrict__ linkv) {
  int idx = blockIdx.x * 256 + threadIdx.x;   // < 4*128*2048 = 1048576
  int b = idx >> 18;
  int de = idx & 262143;
  const float* p = pkv + (size_t)b * 4 * 262144 + de;
  float s = p[0] + p[262144] + p[524288] + p[786432];
  linkv[idx] = f2bf(s * (1.0f / 4096.0f));
}

// Generic bf16 MFMA GEMM, C = A(MxK) @ B. MODE==2 takes B as Bt (NxK) row-major,
// all other modes take B as (KxN) row-major (transposed while staging into LDS).
// MODE 0: hid GEMM   M=16384 N=4096 K=1024; epi: silu(+b_h), split v/gate bf16
// MODE 1: qk GEMM    M=16384 N=128  K=1024; epi: silu(+b_qk), 4 heads (lin_k transposed)
// MODE 2: sim        per-group (z=64) M=N=256 K=128; epi: /G + bias, relu^2 -> attn bf16
// MODE 3: quad+lin   per-group M=256 N=2048 K=256(attn@v)+128(lin_q@lin_kv); epi: *gate
// MODE 4: lin_kv     split-K x4 per batch M=128 N=2048 K=1024; epi: fp32 partial
// MODE 6: final      M=16384 N=1024 K=2048; epi: +b_out +x -> fp32 out
template<int MODE>
__global__ __launch_bounds__(256, 2) void gemm_k(
    const unsigned short* __restrict__ Ag,
    const unsigned short* __restrict__ Bg,
    int lda, int ldb, int kiters, Aux aux)
{
  constexpr bool BT = (MODE == 2);
  __shared__ unsigned short As[BM * BKP];
  __shared__ unsigned short Bs[BN * BKP];

  const int tid  = threadIdx.x;
  const int lane = tid & 63;
  const int wave = tid >> 6;
  const int quad = lane >> 4;
  const int l16  = lane & 15;
  const int wm   = (wave >> 1) * 64;
  const int wn   = (wave & 1) * 64;
  const int bz   = blockIdx.z;
  const int bm   = blockIdx.y * BM;
  const int bn   = blockIdx.x * BN;

  const unsigned short* A = Ag;
  const unsigned short* B = Bg;
  if constexpr (MODE == 2) { A += (size_t)bz * 32768;  B += (size_t)bz * 32768; }
  if constexpr (MODE == 3) { A += (size_t)bz * 65536;  B += (size_t)bz * 524288; }
  if constexpr (MODE == 4) { const int b = bz >> 2, s = bz & 3;
                             A += (size_t)b * 524288 + (size_t)s * 1024;   // (128,4096) cols s*1024..
                             B += (size_t)bz * 2097152; }                  // v rows (b*4096+s*1024)..

  const unsigned short* A2 = nullptr;  // mode3 tail: lin_q group (256 x 128)
  const unsigned short* B2 = nullptr;  // mode3 tail: lin_kv batch (128 x 2048)
  if constexpr (MODE == 3) {
    A2 = aux.a2 + (size_t)bz * 32768;
    B2 = aux.bkv + (size_t)(bz >> 4) * 262144;
  }

  const int arow = tid >> 2;          // staging row (x2: +64)
  const int acol = (tid & 3) * 8;     // staging col (8 bf16 = 16B)
  const int brow = tid >> 4;          // NN staging: k-row (x2: +16)
  const int bcol = (tid & 15) * 8;    // NN staging: n-col

  const f32x4 zero = {0.f, 0.f, 0.f, 0.f};
  f32x4 acc[4][4];
  #pragma unroll
  for (int i = 0; i < 4; ++i)
    #pragma unroll
    for (int j = 0; j < 4; ++j) acc[i][j] = zero;

  for (int kt = 0; kt < kiters; ++kt) {
    const int k0 = kt * BK;

    short8 a0, a1, b0, b1;
    bool tail = false;
    if constexpr (MODE == 3) tail = (kt >= 8);
    if (tail) {
      const int k2 = k0 - 256;  // 0..127 within lin_q/lin_kv K
      a0 = *reinterpret_cast<const short8*>(A2 + (size_t)(bm + arow) * 128 + (k2 + acol));
      a1 = *reinterpret_cast<const short8*>(A2 + (size_t)(bm + arow + 64) * 128 + (k2 + acol));
      b0 = *reinterpret_cast<const short8*>(B2 + (size_t)(k2 + brow) * 2048 + (bn + bcol));
      b1 = *reinterpret_cast<const short8*>(B2 + (size_t)(k2 + brow + 16) * 2048 + (bn + bcol));
    } else {
      a0 = *reinterpret_cast<const short8*>(A + (size_t)(bm + arow) * lda + (k0 + acol));
      a1 = *reinterpret_cast<const short8*>(A + (size_t)(bm + arow + 64) * lda + (k0 + acol));
      if constexpr (BT) {
        b0 = *reinterpret_cast<const short8*>(B + (size_t)(bn + arow) * ldb + (k0 + acol));
        b1 = *reinterpret_cast<const short8*>(B + (size_t)(bn + arow + 64) * ldb + (k0 + acol));
      } else {
        b0 = *reinterpret_cast<const short8*>(B + (size_t)(k0 + brow) * ldb + (bn + bcol));
        b1 = *reinterpret_cast<const short8*>(B + (size_t)(k0 + brow + 16) * ldb + (bn + bcol));
      }
    }

    __syncthreads();  // prior iteration's LDS reads complete
    *reinterpret_cast<short8*>(As + arow * BKP + acol) = a0;
    *reinterpret_cast<short8*>(As + (arow + 64) * BKP + acol) = a1;
    if constexpr (BT) {
      *reinterpret_cast<short8*>(Bs + arow * BKP + acol) = b0;
      *reinterpret_cast<short8*>(Bs + (arow + 64) * BKP + acol) = b1;
    } else {
      U8 u0, u1; u0.v = b0; u1.v = b1;
      #pragma unroll
      for (int e = 0; e < 8; ++e) {
        Bs[(bcol + e) * BKP + brow]      = u0.u[e];
        Bs[(bcol + e) * BKP + brow + 16] = u1.u[e];
      }
    }
    __syncthreads();

    short8 af[4], bfv[4];
    #pragma unroll
    for (int i = 0; i < 4; ++i)
      af[i] = *reinterpret_cast<const short8*>(As + (wm + i * 16 + l16) * BKP + quad * 8);
    #pragma unroll
    for (int j = 0; j < 4; ++j)
      bfv[j] = *reinterpret_cast<const short8*>(Bs + (wn + j * 16 + l16) * BKP + quad * 8);

    #pragma unroll
    for (int i = 0; i < 4; ++i)
      #pragma unroll
      for (int j = 0; j < 4; ++j)
        acc[i][j] = __builtin_amdgcn_mfma_f32_16x16x32_bf16(af[i], bfv[j], acc[i][j], 0, 0, 0);
  }

  // epilogue: D[row=quad*4+r][col=lane&15] per 16x16 tile
  #pragma unroll
  for (int i = 0; i < 4; ++i) {
    #pragma unroll
    for (int j = 0; j < 4; ++j) {
      #pragma unroll
      for (int r = 0; r < 4; ++r) {
        const int row = bm + wm + i * 16 + quad * 4 + r;
        const int col = bn + wn + j * 16 + l16;
        const float v = acc[i][j][r];
        if constexpr (MODE == 0) {
          const float s = silu_f(v + aux.b1[col]);
          if (col < 2048) aux.o16a[(size_t)row * 2048 + col] = f2bf(s);
          else            aux.o16b[(size_t)row * 2048 + (col - 2048)] = f2bf(s);
        } else if constexpr (MODE == 1) {
          const float s = silu_f(v + aux.b1[col]);
          aux.o16a[(size_t)row * 128 + col] = f2bf(s * aux.gamma[col]       + aux.beta[col]);        // quad_q
          aux.o16b[(size_t)row * 128 + col] = f2bf(s * aux.gamma[128 + col] + aux.beta[128 + col]);  // lin_q
          aux.o16c[(size_t)row * 128 + col] = f2bf(s * aux.gamma[256 + col] + aux.beta[256 + col]);  // quad_k
          const int b = row >> 12, t = row & 4095;                                                   // lin_k^T
          aux.o16d[((size_t)b * 128 + col) * 4096 + t] = f2bf(s * aux.gamma[384 + col] + aux.beta[384 + col]);
        } else if constexpr (MODE == 2) {
          float s = v * (1.0f / 256.0f) + aux.biastab[col - row + 255];
          s = fmaxf(s, 0.0f);
          aux.o16a[(size_t)bz * 65536 + row * 256 + col] = f2bf(s * s);
        } else if constexpr (MODE == 3) {
          const size_t idx = ((size_t)bz * 256 + row) * 2048 + col;
          aux.o16a[idx] = f2bf(v * bf2f(aux.gate[idx]));
        } else if constexpr (MODE == 4) {
          aux.o32[(size_t)bz * 262144 + (size_t)row * 2048 + col] = v;
        } else if constexpr (MODE == 6) {
          const size_t idx = (size_t)row * 1024 + col;
          aux.o32[idx] = v + aux.b1[col] + aux.x[idx];
        }
      }
    }
  }
}

extern "C" void kernel_launch(void* const* d_in, const int* in_sizes, int n_in,
                              void* d_out, int out_size, void* d_ws, size_t ws_size,
                              hipStream_t stream) {
  (void)in_sizes; (void)n_in; (void)out_size; (void)ws_size;
  const float* x     = (const float*)d_in[0];
  const float* ln_g  = (const float*)d_in[1];
  const float* ln_b  = (const float*)d_in[2];
  const float* W_h   = (const float*)d_in[3];
  const float* b_h   = (const float*)d_in[4];
  const float* W_qk  = (const float*)d_in[5];
  const float* b_qk  = (const float*)d_in[6];
  const float* osg   = (const float*)d_in[7];
  const float* osb   = (const float*)d_in[8];
  const float* rel   = (const float*)d_in[9];
  const float* W_out = (const float*)d_in[10];
  const float* b_out = (const float*)d_in[11];
  float* out = (float*)d_out;

  char* w = (char*)d_ws;
  size_t off = 0;
  auto alloc = [&](size_t bytes) { char* p = w + off; off += (bytes + 255) & ~(size_t)255; return p; };

  // ---- arena R (members dead before mode 3; gated aliases R[0..64M)) ----
  unsigned short* normed = (unsigned short*)alloc(16384ull * 1024 * 2);  // 32M, dead after mode1
  unsigned short* whb    = (unsigned short*)alloc(1024ull * 4096 * 2);   //  8M, dead after mode0
  unsigned short* qq     = (unsigned short*)alloc(16384ull * 128 * 2);   //  4M, dead after mode2
  unsigned short* qkk    = (unsigned short*)alloc(16384ull * 128 * 2);   //  4M, dead after mode2
  unsigned short* linkT  = (unsigned short*)alloc(4ull * 128 * 4096 * 2);//  4M, dead after mode4
  float*          pkv    = (float*)alloc(16ull * 128 * 2048 * 4);        // 16M, dead after kvred
  // ---- live-through buffers ----
  unsigned short* wqkb   = (unsigned short*)alloc(1024ull * 128 * 2);
  unsigned short* woutb  = (unsigned short*)alloc(2048ull * 1024 * 2);
  unsigned short* vbuf   = (unsigned short*)alloc(16384ull * 2048 * 2);  // 64M
  unsigned short* gate   = (unsigned short*)alloc(16384ull * 2048 * 2);  // 64M
  unsigned short* lq     = (unsigned short*)alloc(16384ull * 128 * 2);
  unsigned short* attn   = (unsigned short*)alloc(64ull * 256 * 256 * 2);//  8M
  unsigned short* linkv  = (unsigned short*)alloc(4ull * 128 * 2048 * 2);
  float*          btab   = (float*)alloc(511 * 4);
  unsigned short* gated  = (unsigned short*)w;  // alias arena R (64M needed, 68M available)

  cast_k<<<4096, 256, 0, stream>>>(W_h,  whb,   1048576);
  cast_k<<<128,  256, 0, stream>>>(W_qk, wqkb,  32768);
  cast_k<<<2048, 256, 0, stream>>>(W_out, woutb, 524288);
  bias_k<<<2,    256, 0, stream>>>(rel, btab);
  ln_k  <<<16384, 256, 0, stream>>>(x, ln_g, ln_b, normed);

  Aux a0{}; a0.b1 = b_h; a0.o16a = vbuf; a0.o16b = gate;
  gemm_k<0><<<dim3(32, 128, 1), 256, 0, stream>>>(normed, whb, 1024, 4096, 32, a0);

  Aux a1{}; a1.b1 = b_qk; a1.gamma = osg; a1.beta = osb;
  a1.o16a = qq; a1.o16b = lq; a1.o16c = qkk; a1.o16d = linkT;
  gemm_k<1><<<dim3(1, 128, 1), 256, 0, stream>>>(normed, wqkb, 1024, 128, 32, a1);

  Aux a2x{}; a2x.biastab = btab; a2x.o16a = attn;
  gemm_k<2><<<dim3(2, 2, 64), 256, 0, stream>>>(qq, qkk, 128, 128, 4, a2x);

  Aux a4{}; a4.o32 = pkv;
  gemm_k<4><<<dim3(16, 1, 16), 256, 0, stream>>>(linkT, vbuf, 4096, 2048, 32, a4);

  kvred_k<<<4096, 256, 0, stream>>>(pkv, linkv);

  Aux a3{}; a3.a2 = lq; a3.bkv = linkv; a3.gate = gate; a3.o16a = gated;
  gemm_k<3><<<dim3(16, 2, 64), 256, 0, stream>>>(attn, vbuf, 256, 2048, 12, a3);

  Aux a6{}; a6.b1 = b_out; a6.x = x; a6.o32 = out;
  gemm_k<6><<<dim3(8, 128, 1), 256, 0, stream>>>(gated, woutb, 2048, 1024, 64, a6);
}

// Round 3
// 596.283 us; speedup vs baseline: 2.1101x; 2.1101x over previous
//
#include <hip/hip_runtime.h>
#include <hip/hip_bf16.h>

// FLASH/GAU block: B=4 N=4096 DIM=1024 QK=128 G=256, all GEMMs in TN form
// (A: MxK row-major, B: NxK row-major, K contiguous) via one templated bf16
// MFMA kernel: 128x128x32 tile, 4 waves, 16x16x32 MFMA, global_load_lds
// width-16 staging (m97 structure), fused per-mode epilogues.

typedef __attribute__((ext_vector_type(8))) short short8;
typedef __attribute__((ext_vector_type(4))) float f32x4;

#define BM 128
#define BN 128
#define BK 32

struct Aux {
  const float* b1;              // bias vec (b_h / b_qk / b_out)
  const float* x;               // residual (mode6)
  const float* gamma;           // os_gamma (mode1)
  const float* beta;            // os_beta  (mode1)
  const float* biastab;         // rel-pos table (mode2)
  const unsigned short* a2;     // mode3 tail A: lin_q (16384x128)
  const unsigned short* bkv;    // mode3 tail B: linkvT (4x2048x128)
  const unsigned short* gate;   // mode3: bf16 gate
  unsigned short* o16a;
  unsigned short* o16b;
  unsigned short* o16c;
  unsigned short* o16d;
  float* o32;
};

__device__ __forceinline__ float bf2f(unsigned short u) {
  union { float f; unsigned int i; } w; w.i = ((unsigned int)u) << 16; return w.f;
}
__device__ __forceinline__ unsigned short f2bf(float f) {
  union { float f; unsigned int i; } w; w.f = f;
  unsigned int x = w.i;
  return (unsigned short)((x + 0x7FFFu + ((x >> 16) & 1u)) >> 16);
}
__device__ __forceinline__ float silu_f(float z) { return z / (1.0f + __expf(-z)); }

// async global->LDS, 16B per lane; lptr must be the wave-uniform base
__device__ __forceinline__ void async_cp16(const unsigned short* g, unsigned short* l) {
  __builtin_amdgcn_global_load_lds(
      (const __attribute__((address_space(1))) void*)g,
      (__attribute__((address_space(3))) void*)l, 16, 0, 0);
}

__device__ __forceinline__ float block_sum(float v) {
  #pragma unroll
  for (int o = 32; o > 0; o >>= 1) v += __shfl_down(v, o, 64);
  __shared__ float sh[4];
  __syncthreads();
  if ((threadIdx.x & 63) == 0) sh[threadIdx.x >> 6] = v;
  __syncthreads();
  return sh[0] + sh[1] + sh[2] + sh[3];
}

// LayerNorm over DIM=1024, one block per row, output bf16.
__global__ __launch_bounds__(256) void ln_k(const float* __restrict__ x,
                                            const float* __restrict__ g,
                                            const float* __restrict__ b,
                                            unsigned short* __restrict__ out) {
  const int row = blockIdx.x;
  const int tid = threadIdx.x;
  const float4 xv = ((const float4*)(x + (size_t)row * 1024))[tid];
  float s = xv.x + xv.y + xv.z + xv.w;
  s = block_sum(s);
  const float mu = s * (1.0f / 1024.0f);
  const float d0 = xv.x - mu, d1 = xv.y - mu, d2 = xv.z - mu, d3 = xv.w - mu;
  float q = d0 * d0 + d1 * d1 + d2 * d2 + d3 * d3;
  q = block_sum(q);
  const float rstd = rsqrtf(q * (1.0f / 1024.0f) + 1e-5f);
  const float4 gv = ((const float4*)g)[tid];
  const float4 bv = ((const float4*)b)[tid];
  unsigned short* o = out + (size_t)row * 1024 + tid * 4;
  o[0] = f2bf(d0 * rstd * gv.x + bv.x);
  o[1] = f2bf(d1 * rstd * gv.y + bv.y);
  o[2] = f2bf(d2 * rstd * gv.z + bv.z);
  o[3] = f2bf(d3 * rstd * gv.w + bv.w);
}

// transpose-cast: in[K][N] fp32 -> out[N][K] bf16, 64x64 LDS tiles
__global__ __launch_bounds__(256) void tc_k(const float* __restrict__ in,
                                            unsigned short* __restrict__ out,
                                            int K, int N) {
  __shared__ unsigned short L[64][65];
  const int t = threadIdx.x;
  const int k0 = blockIdx.y * 64, n0 = blockIdx.x * 64;
  const int r = t >> 4, c4 = (t & 15) * 4;
  #pragma unroll
  for (int rr = 0; rr < 4; ++rr) {
    const int kk = rr * 16 + r;
    const float4 f = ((const float4*)(in + (size_t)(k0 + kk) * N + n0))[t & 15];
    L[kk][c4 + 0] = f2bf(f.x); L[kk][c4 + 1] = f2bf(f.y);
    L[kk][c4 + 2] = f2bf(f.z); L[kk][c4 + 3] = f2bf(f.w);
  }
  __syncthreads();
  #pragma unroll
  for (int rr = 0; rr < 4; ++rr) {
    const int nn = rr * 16 + r;
    ushort4 u;
    u.x = L[c4 + 0][nn]; u.y = L[c4 + 1][nn];
    u.z = L[c4 + 2][nn]; u.w = L[c4 + 3][nn];
    ((ushort4*)(out + (size_t)(n0 + nn) * K + k0))[t & 15] = u;
  }
}

// rel-pos bias table: tab[d + 255] for d = j - i in [-255, 255]
__global__ void bias_k(const float* __restrict__ rel, float* __restrict__ tab) {
  int idx = blockIdx.x * 256 + threadIdx.x;
  if (idx >= 511) return;
  int d = idx - 255;       // j - i
  int n = -d;              // i - j
  int ret = (n < 0) ? 16 : 0;
  int a = (n < 0) ? -n : n;
  int bucket;
  if (a < 8) {
    bucket = ret + a;
  } else {
    float t = __logf((float)a * 0.125f) / 2.7725887298583984f * 8.0f;
    int vl = 8 + (int)t;
    if (vl > 15) vl = 15;
    bucket = ret + vl;
  }
  tab[idx] = rel[bucket] * 11.313708498984761f;  // * sqrt(QK)
}

// reduce 4 split-K partials of pkvT[b][s][e][d], scale 1/N, cast -> linkvT[b][e][d]
__global__ void kvred_k(const float* __restrict__ pkv, unsigned short* __restrict__ linkvT) {
  int i4 = blockIdx.x * 256 + threadIdx.x;   // < 262144 (float4 units)
  const int b = i4 >> 16, rem = i4 & 65535;
  const float4* p = (const float4*)(pkv + (size_t)b * 1048576) + rem;
  const float4 p0 = p[0], p1 = p[65536], p2 = p[131072], p3 = p[196608];
  ushort4 u;
  u.x = f2bf((p0.x + p1.x + p2.x + p3.x) * (1.0f / 4096.0f));
  u.y = f2bf((p0.y + p1.y + p2.y + p3.y) * (1.0f / 4096.0f));
  u.z = f2bf((p0.z + p1.z + p2.z + p3.z) * (1.0f / 4096.0f));
  u.w = f2bf((p0.w + p1.w + p2.w + p3.w) * (1.0f / 4096.0f));
  ((ushort4*)(linkvT + (size_t)b * 262144))[rem] = u;
}

// TN bf16 MFMA GEMM: C = A(MxK) @ B(NxK)^T, K contiguous in both.
// MODE 0: hid   M=16384 N=4096 K=1024; epi silu(+b_h): cols<2048 -> vT[b][e][t], else gate
// MODE 1: qk    M=16384 N=128  K=1024; epi silu(+b_qk): qq/lq/qkk row-major + linkT[b][d][t]
// MODE 2: sim   per-group M=N=256 K=128; epi /G +bias, relu^2 -> attn
// MODE 3: quad+lin per-group M=256 N=2048 K=256(attn@vT)+128(lq@linkvT); epi *gate
// MODE 4: lin_kv split-K x4 per batch M=128(d) N=2048(e) K=1024; epi fp32 pkvT[e][d]
// MODE 6: final M=16384 N=1024 K=2048; epi +b_out +x -> fp32 out
template<int MODE>
__global__ __launch_bounds__(256, 2) void gemm_k(
    const unsigned short* __restrict__ Ag,
    const unsigned short* __restrict__ Bg,
    int lda, int ldb, int kiters, Aux aux)
{
  __shared__ unsigned short As[BM * BK];
  __shared__ unsigned short Bs[BN * BK];

  const int tid  = threadIdx.x;
  const int lane = tid & 63;
  const int wave = tid >> 6;
  const int quad = lane >> 4;
  const int l16  = lane & 15;
  const int wm   = (wave >> 1) * 64;
  const int wn   = (wave & 1) * 64;
  const int bz   = blockIdx.z;
  const int bm   = blockIdx.y * BM;
  const int bn   = blockIdx.x * BN;

  const unsigned short* A = Ag;
  const unsigned short* B = Bg;
  if constexpr (MODE == 2) { A += (size_t)bz * 32768;  B += (size_t)bz * 32768; }
  if constexpr (MODE == 3) { A += (size_t)bz * 65536;                       // attn group
                             B += (size_t)(bz >> 4) * 8388608 + (size_t)(bz & 15) * 256; } // vT + g*256
  if constexpr (MODE == 4) { const int b = bz >> 2, s = bz & 3;
                             A += (size_t)b * 524288 + (size_t)s * 1024;    // linkT cols s*1024..
                             B += (size_t)b * 8388608 + (size_t)s * 1024; } // vT cols s*1024..

  const unsigned short* A2 = nullptr;
  const unsigned short* B2 = nullptr;
  if constexpr (MODE == 3) {
    A2 = aux.a2 + (size_t)bz * 32768;            // lq group (256x128)
    B2 = aux.bkv + (size_t)(bz >> 4) * 262144;   // linkvT batch (2048x128)
  }

  const int srow = wave * 32 + (lane >> 2);  // staging row (+16 for 2nd issue)
  const int scol = (lane & 3) * 8;           // staging col (8 bf16 = 16B)
  unsigned short* lA = As + wave * 1024;     // wave-uniform LDS bases
  unsigned short* lB = Bs + wave * 1024;

  const f32x4 zero = {0.f, 0.f, 0.f, 0.f};
  f32x4 acc[4][4];
  #pragma unroll
  for (int i = 0; i < 4; ++i)
    #pragma unroll
    for (int j = 0; j < 4; ++j) acc[i][j] = zero;

  for (int kt = 0; kt < kiters; ++kt) {
    const unsigned short* pa = A;
    const unsigned short* pb = B;
    int la = lda, lb = ldb, kk = kt * BK;
    if constexpr (MODE == 3) {
      if (kt >= 8) { pa = A2; pb = B2; la = 128; lb = 128; kk -= 256; }
    }

    __syncthreads();  // prior iteration's LDS reads complete
    async_cp16(pa + (size_t)(bm + srow) * la + kk + scol, lA);
    async_cp16(pa + (size_t)(bm + srow + 16) * la + kk + scol, lA + 512);
    async_cp16(pb + (size_t)(bn + srow) * lb + kk + scol, lB);
    async_cp16(pb + (size_t)(bn + srow + 16) * lb + kk + scol, lB + 512);
    __syncthreads();  // drains vmcnt (compiler) -> staged data visible

    short8 af[4], bfv[4];
    #pragma unroll
    for (int i = 0; i < 4; ++i)
      af[i] = *reinterpret_cast<const short8*>(As + (wm + i * 16 + l16) * BK + quad * 8);
    #pragma unroll
    for (int j = 0; j < 4; ++j)
      bfv[j] = *reinterpret_cast<const short8*>(Bs + (wn + j * 16 + l16) * BK + quad * 8);

    #pragma unroll
    for (int i = 0; i < 4; ++i)
      #pragma unroll
      for (int j = 0; j < 4; ++j)
        acc[i][j] = __builtin_amdgcn_mfma_f32_16x16x32_bf16(af[i], bfv[j], acc[i][j], 0, 0, 0);
  }

  // epilogue: D[row=quad*4+r][col=l16] per 16x16 tile
  #pragma unroll
  for (int i = 0; i < 4; ++i) {
    #pragma unroll
    for (int j = 0; j < 4; ++j) {
      const int row0 = bm + wm + i * 16 + quad * 4;
      const int col  = bn + wn + j * 16 + l16;
      if constexpr (MODE == 0) {
        const float bb = aux.b1[col];
        float s[4];
        #pragma unroll
        for (int r = 0; r < 4; ++r) s[r] = silu_f(acc[i][j][r] + bb);
        if (col < 2048) {          // vT[b][e][t] (uniform per block: BN | 2048)
          const int b = row0 >> 12, t = row0 & 4095;
          ushort4 u; u.x = f2bf(s[0]); u.y = f2bf(s[1]); u.z = f2bf(s[2]); u.w = f2bf(s[3]);
          *(ushort4*)(aux.o16a + (size_t)b * 8388608 + (size_t)col * 4096 + t) = u;
        } else {                   // gate row-major
          #pragma unroll
          for (int r = 0; r < 4; ++r)
            aux.o16b[(size_t)(row0 + r) * 2048 + (col - 2048)] = f2bf(s[r]);
        }
      } else if constexpr (MODE == 1) {
        const float bb = aux.b1[col];
        float s[4];
        #pragma unroll
        for (int r = 0; r < 4; ++r) s[r] = silu_f(acc[i][j][r] + bb);
        #pragma unroll
        for (int r = 0; r < 4; ++r) {
          const size_t idx = (size_t)(row0 + r) * 128 + col;
          aux.o16a[idx] = f2bf(s[r] * aux.gamma[col]       + aux.beta[col]);        // quad_q
          aux.o16b[idx] = f2bf(s[r] * aux.gamma[128 + col] + aux.beta[128 + col]);  // lin_q
          aux.o16c[idx] = f2bf(s[r] * aux.gamma[256 + col] + aux.beta[256 + col]);  // quad_k
        }
        const int b = row0 >> 12, t = row0 & 4095;                                  // lin_k^T
        const float g4 = aux.gamma[384 + col], b4 = aux.beta[384 + col];
        ushort4 u;
        u.x = f2bf(s[0] * g4 + b4); u.y = f2bf(s[1] * g4 + b4);
        u.z = f2bf(s[2] * g4 + b4); u.w = f2bf(s[3] * g4 + b4);
        *(ushort4*)(aux.o16d + (size_t)b * 524288 + (size_t)col * 4096 + t) = u;
      } else if constexpr (MODE == 2) {
        #pragma unroll
        for (int r = 0; r < 4; ++r) {
          float s = acc[i][j][r] * (1.0f / 256.0f) + aux.biastab[col - (row0 + r) + 255];
          s = fmaxf(s, 0.0f);
          aux.o16a[(size_t)bz * 65536 + (size_t)(row0 + r) * 256 + col] = f2bf(s * s);
        }
      } else if constexpr (MODE == 3) {
        #pragma unroll
        for (int r = 0; r < 4; ++r) {
          const size_t idx = ((size_t)bz * 256 + row0 + r) * 2048 + col;
          aux.o16a[idx] = f2bf(acc[i][j][r] * bf2f(aux.gate[idx]));
        }
      } else if constexpr (MODE == 4) {
        float4 u; u.x = acc[i][j][0]; u.y = acc[i][j][1]; u.z = acc[i][j][2]; u.w = acc[i][j][3];
        *(float4*)(aux.o32 + (size_t)bz * 262144 + (size_t)col * 128 + row0) = u;
      } else if constexpr (MODE == 6) {
        #pragma unroll
        for (int r = 0; r < 4; ++r) {
          const size_t idx = (size_t)(row0 + r) * 1024 + col;
          aux.o32[idx] = acc[i][j][r] + aux.b1[col] + aux.x[idx];
        }
      }
    }
  }
}

extern "C" void kernel_launch(void* const* d_in, const int* in_sizes, int n_in,
                              void* d_out, int out_size, void* d_ws, size_t ws_size,
                              hipStream_t stream) {
  (void)in_sizes; (void)n_in; (void)out_size; (void)ws_size;
  const float* x     = (const float*)d_in[0];
  const float* ln_g  = (const float*)d_in[1];
  const float* ln_b  = (const float*)d_in[2];
  const float* W_h   = (const float*)d_in[3];
  const float* b_h   = (const float*)d_in[4];
  const float* W_qk  = (const float*)d_in[5];
  const float* b_qk  = (const float*)d_in[6];
  const float* osg   = (const float*)d_in[7];
  const float* osb   = (const float*)d_in[8];
  const float* rel   = (const float*)d_in[9];
  const float* W_out = (const float*)d_in[10];
  const float* b_out = (const float*)d_in[11];
  float* out = (float*)d_out;

  char* w = (char*)d_ws;
  size_t off = 0;
  auto alloc = [&](size_t bytes) { char* p = w + off; off += (bytes + 255) & ~(size_t)255; return p; };

  // ---- arena R (all dead before mode 3 writes `gated`, which aliases R) ----
  unsigned short* normed = (unsigned short*)alloc(16384ull * 1024 * 2);   // 32M, dead after mode1
  unsigned short* whT    = (unsigned short*)alloc(4096ull * 1024 * 2);    //  8M, dead after mode0
  unsigned short* qq     = (unsigned short*)alloc(16384ull * 128 * 2);    //  4M, dead after mode2
  unsigned short* qkk    = (unsigned short*)alloc(16384ull * 128 * 2);    //  4M, dead after mode2
  unsigned short* linkT  = (unsigned short*)alloc(4ull * 128 * 4096 * 2); //  4M, dead after mode4
  float*          pkvT   = (float*)alloc(16ull * 2048 * 128 * 4);         // 16M, dead after kvred
  unsigned short* wqkT   = (unsigned short*)alloc(128ull * 1024 * 2);     // 256K, dead after mode1
  // ---- live-through buffers ----
  unsigned short* woutT  = (unsigned short*)alloc(1024ull * 2048 * 2);
  unsigned short* vT     = (unsigned short*)alloc(4ull * 2048 * 4096 * 2); // 64M
  unsigned short* gate   = (unsigned short*)alloc(16384ull * 2048 * 2);    // 64M
  unsigned short* lq     = (unsigned short*)alloc(16384ull * 128 * 2);
  unsigned short* attn   = (unsigned short*)alloc(64ull * 256 * 256 * 2);  //  8M
  unsigned short* linkvT = (unsigned short*)alloc(4ull * 2048 * 128 * 2);
  float*          btab   = (float*)alloc(511 * 4);
  unsigned short* gated  = (unsigned short*)w;  // alias arena R (64M needed, ~68M there)

  tc_k<<<dim3(64, 16), 256, 0, stream>>>(W_h,   whT,   1024, 4096);
  tc_k<<<dim3(2, 16),  256, 0, stream>>>(W_qk,  wqkT,  1024, 128);
  tc_k<<<dim3(16, 32), 256, 0, stream>>>(W_out, woutT, 2048, 1024);
  bias_k<<<2, 256, 0, stream>>>(rel, btab);
  ln_k<<<16384, 256, 0, stream>>>(x, ln_g, ln_b, normed);

  Aux a0{}; a0.b1 = b_h; a0.o16a = vT; a0.o16b = gate;
  gemm_k<0><<<dim3(32, 128, 1), 256, 0, stream>>>(normed, whT, 1024, 1024, 32, a0);

  Aux a1{}; a1.b1 = b_qk; a1.gamma = osg; a1.beta = osb;
  a1.o16a = qq; a1.o16b = lq; a1.o16c = qkk; a1.o16d = linkT;
  gemm_k<1><<<dim3(1, 128, 1), 256, 0, stream>>>(normed, wqkT, 1024, 1024, 32, a1);

  Aux a2x{}; a2x.biastab = btab; a2x.o16a = attn;
  gemm_k<2><<<dim3(2, 2, 64), 256, 0, stream>>>(qq, qkk, 128, 128, 4, a2x);

  Aux a4{}; a4.o32 = pkvT;
  gemm_k<4><<<dim3(16, 1, 16), 256, 0, stream>>>(linkT, vT, 4096, 4096, 8, a4);

  kvred_k<<<1024, 256, 0, stream>>>(pkvT, linkvT);

  Aux a3{}; a3.a2 = lq; a3.bkv = linkvT; a3.gate = gate; a3.o16a = gated;
  gemm_k<3><<<dim3(16, 2, 64), 256, 0, stream>>>(attn, vT, 256, 4096, 12, a3);

  Aux a6{}; a6.b1 = b_out; a6.x = x; a6.o32 = out;
  gemm_k<6><<<dim3(8, 128, 1), 256, 0, stream>>>(gated, woutT, 2048, 2048, 64, a6);
}